// Round 2
// baseline (385.689 us; speedup 1.0000x reference)
//
#include <hip/hip_runtime.h>

// LIF neuron layer forward (fp32):
//   v_t = BETA * v_{t-1} * (1 - s_{t-1}) + i_t   (hard reset)
//   s_t = (v_t >= 1.0) ? 1 : 0
// Outputs flat-concat: spikes (B,T,H), membrane (B,T,H), v_final (B,H)
// B=16, T=1024, H=2048.
//
// Memory-bound: 134 MB read + 269 MB write ≈ 403 MB -> ~64 us @ 6.3 TB/s.
//
// R1 post-mortem: 367 us = ~860 cyc/step = one full HBM latency per time-step;
// the two-buffer prefetch collapsed (bulk cur=nxt copy created a drain point).
// R2: rolling circular prefetch (consume buf[j], immediately refill for t+D),
// float2 per lane (2 independent recurrences, 512 B/wave load), nontemporal
// load/store, 1 wave on each of the 256 CUs.

constexpr int B_ = 16;
constexpr int T_ = 1024;
constexpr int H_ = 2048;
constexpr int H2 = H_ / 2;          // float2 columns per row = 1024
constexpr float BETA = 0.904837f;
constexpr int D = 16;               // prefetch depth (loads in flight / thread)

typedef __attribute__((ext_vector_type(2))) float fx2;

__global__ __launch_bounds__(64) void lif_fwd_kernel(
    const fx2* __restrict__ in,   // (B,T,H2)
    const fx2* __restrict__ v0,   // (B,H2)
    fx2* __restrict__ sp,         // (B,T,H2)
    fx2* __restrict__ mem,        // (B,T,H2)
    fx2* __restrict__ vf)         // (B,H2)
{
    const int idx = blockIdx.x * 64 + threadIdx.x;   // b*H2 + h2, < 16384
    const int b  = idx >> 10;                        // / H2
    const int h2 = idx & (H2 - 1);                   // % H2
    const size_t base = (size_t)b * T_ * H2 + (size_t)h2;

    const fx2* __restrict__ ip = in + base;
    fx2* __restrict__ spp = sp + base;
    fx2* __restrict__ mp  = mem + base;

    fx2 vv = v0[idx];
    float v0r = vv[0], v1r = vv[1];
    float s0r = 0.0f, s1r = 0.0f;

    // Prime the circular prefetch buffer: t = 0..D-1.
    fx2 buf[D];
#pragma unroll
    for (int j = 0; j < D; ++j)
        buf[j] = __builtin_nontemporal_load(ip + (size_t)j * H2);

    // Steady state: consume buf[j] (loaded D steps ago), immediately refill it
    // with t0+D+j. D loads stay continuously in flight; no bulk copy, no drain.
    int t0 = 0;
    for (; t0 < T_ - D; t0 += D) {
#pragma unroll
        for (int j = 0; j < D; ++j) {
            const fx2 x = buf[j];
            buf[j] = __builtin_nontemporal_load(ip + (size_t)(t0 + D + j) * H2);

            // s in {0,1}: (1-s) multiply is exact -> FMA contraction is
            // bit-identical to the numpy two-step reference.
            v0r = BETA * v0r * (1.0f - s0r) + x[0];
            v1r = BETA * v1r * (1.0f - s1r) + x[1];
            s0r = (v0r >= 1.0f) ? 1.0f : 0.0f;
            s1r = (v1r >= 1.0f) ? 1.0f : 0.0f;

            const size_t o = (size_t)(t0 + j) * H2;
            fx2 sv; sv[0] = s0r; sv[1] = s1r;
            fx2 mv; mv[0] = v0r; mv[1] = v1r;
            __builtin_nontemporal_store(sv, spp + o);
            __builtin_nontemporal_store(mv, mp + o);
        }
    }

    // Tail: last D steps, no further loads.
#pragma unroll
    for (int j = 0; j < D; ++j) {
        const fx2 x = buf[j];
        v0r = BETA * v0r * (1.0f - s0r) + x[0];
        v1r = BETA * v1r * (1.0f - s1r) + x[1];
        s0r = (v0r >= 1.0f) ? 1.0f : 0.0f;
        s1r = (v1r >= 1.0f) ? 1.0f : 0.0f;

        const size_t o = (size_t)(t0 + j) * H2;
        fx2 sv; sv[0] = s0r; sv[1] = s1r;
        fx2 mv; mv[0] = v0r; mv[1] = v1r;
        __builtin_nontemporal_store(sv, spp + o);
        __builtin_nontemporal_store(mv, mp + o);
    }

    fx2 vfv; vfv[0] = v0r; vfv[1] = v1r;
    vf[idx] = vfv;
}

extern "C" void kernel_launch(void* const* d_in, const int* in_sizes, int n_in,
                              void* d_out, int out_size, void* d_ws, size_t ws_size,
                              hipStream_t stream) {
    const fx2* in = (const fx2*)d_in[0];   // (B,T,H)
    const fx2* v0 = (const fx2*)d_in[1];   // (B,H)

    float* out = (float*)d_out;
    const size_t n_bth = (size_t)B_ * T_ * H_;
    fx2* sp  = (fx2*)out;                      // spikes
    fx2* mem = (fx2*)(out + n_bth);            // membrane
    fx2* vf  = (fx2*)(out + 2 * n_bth);        // v_final

    const int threads = B_ * H2;               // 16384 float2 lanes
    const int block = 64;                      // one wave per block
    const int grid = threads / block;          // 256 blocks -> 1 per CU
    lif_fwd_kernel<<<grid, block, 0, stream>>>(in, v0, sp, mem, vf);
}

// Round 3
// 357.229 us; speedup vs baseline: 1.0797x; 1.0797x over previous
//
#include <hip/hip_runtime.h>

// LIF neuron layer forward (fp32):
//   v_t = BETA * v_{t-1} * (1 - s_{t-1}) + i_t   (hard reset)
//   s_t = (v_t >= 1.0) ? 1 : 0
// Outputs flat-concat: spikes (B,T,H), membrane (B,T,H), v_final (B,H)
// B=16, T=1024, H=2048.  Memory-bound: ~403 MB -> ~64 us @ 6.3 TB/s.
//
// R1/R2 post-mortem: both register-prefetch schemes ran at exactly one HBM
// latency per time-step (367/385 us) -- the compiler never kept the register
// prefetch loads in flight. R3 uses the HW-verified m97 staging pattern:
// __builtin_amdgcn_global_load_lds (width 16) into double-buffered LDS, with
// __syncthreads() at the TOP of the chunk loop so the sync waits only on the
// chunk we're about to consume while the next chunk's loads fly over compute.
//
// One dwordx4 staging op covers TWO time-steps: lanes 0..31 load step t's
// 512 B row, lanes 32..63 load step t+1's row (per-lane global address,
// wave-uniform LDS dest + lane*16) -> LDS ends up contiguous as [step][lane].

constexpr int B_ = 16;
constexpr int T_ = 1024;
constexpr int H_ = 2048;
constexpr int H2 = H_ / 2;           // float2 columns per row = 1024
constexpr float BETA = 0.904837f;
constexpr int C  = 32;               // time-steps per chunk
constexpr int NCH = T_ / C;          // 32 chunks
constexpr int PAIRS = C / 2;         // 16 staging ops per chunk

typedef __attribute__((ext_vector_type(2))) float fx2;

__device__ __forceinline__ void async_copy16(const void* g, void* s) {
    // global -> LDS direct copy, 16 B per lane. LDS dest = uniform base + lane*16.
    __builtin_amdgcn_global_load_lds(
        (const __attribute__((address_space(1))) void*)g,
        (__attribute__((address_space(3))) void*)s,
        16, 0, 0);
}

__global__ __launch_bounds__(64) void lif_fwd_kernel(
    const float* __restrict__ in,   // (B,T,H)
    const float* __restrict__ v0,   // (B,H)
    fx2* __restrict__ sp,           // (B,T,H2)
    fx2* __restrict__ mem,          // (B,T,H2)
    fx2* __restrict__ vf)           // (B,H2)
{
    __shared__ fx2 lds_buf[2][C * 64];   // 2 x 16 KB

    const int lane = threadIdx.x;        // 0..63
    const int w    = blockIdx.x;         // 0..255 (one wave per block)
    const int b    = w >> 4;             // batch row
    const int colb = (w & 15) * 64;      // fx2 column base of this wave

    const size_t seq_base = (size_t)b * T_ * H2 + colb;   // fx2 units

    // Staging source: lanes 0..31 -> step (t), lanes 32..63 -> step (t+1).
    const int sel = lane >> 5;           // 0 or 1
    const char* stage_base = (const char*)in + seq_base * 8
                           + (size_t)sel * (H2 * 8)       // +1 row for hi lanes
                           + (size_t)(lane & 31) * 16;    // 16 B per lane

    fx2* __restrict__ spp = sp  + seq_base + lane;
    fx2* __restrict__ mpp = mem + seq_base + lane;

    const int vidx = b * H2 + colb + lane;
    const fx2 vv = ((const fx2*)v0)[vidx];
    float v0r = vv[0], v1r = vv[1];
    float s0r = 0.0f, s1r = 0.0f;

    // Prologue: stage chunk 0 into buffer 0.
#pragma unroll
    for (int p = 0; p < PAIRS; ++p)
        async_copy16(stage_base + (size_t)(2 * p) * (H2 * 8),
                     &lds_buf[0][p * 128]);

    for (int c = 0; c < NCH; ++c) {
        // Sync BEFORE issuing next chunk's loads: the implied vmcnt drain here
        // waits only on chunk c's staging (and prior stores), so chunk c+1's
        // loads overlap the whole compute phase below.
        __syncthreads();

        if (c + 1 < NCH) {
            const char* gb = stage_base + (size_t)(c + 1) * C * (H2 * 8);
            const int nb = (c + 1) & 1;
#pragma unroll
            for (int p = 0; p < PAIRS; ++p)
                async_copy16(gb + (size_t)(2 * p) * (H2 * 8),
                             &lds_buf[nb][p * 128]);
        }

        const fx2* lbuf = lds_buf[c & 1];
        const size_t obase = (size_t)c * C * H2;
#pragma unroll
        for (int s = 0; s < C; ++s) {
            const fx2 x = lbuf[s * 64 + lane];   // 2-way bank alias: free

            // s in {0,1}: (1-s) multiply is exact -> FMA contraction is
            // bit-identical to the numpy two-step reference.
            v0r = BETA * v0r * (1.0f - s0r) + x[0];
            v1r = BETA * v1r * (1.0f - s1r) + x[1];
            s0r = (v0r >= 1.0f) ? 1.0f : 0.0f;
            s1r = (v1r >= 1.0f) ? 1.0f : 0.0f;

            const size_t o = obase + (size_t)s * H2;
            fx2 sv; sv[0] = s0r; sv[1] = s1r;
            fx2 mv; mv[0] = v0r; mv[1] = v1r;
            __builtin_nontemporal_store(sv, spp + o);
            __builtin_nontemporal_store(mv, mpp + o);
        }
    }

    fx2 vfv; vfv[0] = v0r; vfv[1] = v1r;
    vf[vidx] = vfv;
}

extern "C" void kernel_launch(void* const* d_in, const int* in_sizes, int n_in,
                              void* d_out, int out_size, void* d_ws, size_t ws_size,
                              hipStream_t stream) {
    const float* in = (const float*)d_in[0];   // (B,T,H)
    const float* v0 = (const float*)d_in[1];   // (B,H)

    float* out = (float*)d_out;
    const size_t n_bth = (size_t)B_ * T_ * H_;
    fx2* sp  = (fx2*)out;                      // spikes
    fx2* mem = (fx2*)(out + n_bth);            // membrane
    fx2* vf  = (fx2*)(out + 2 * n_bth);        // v_final

    const int grid = B_ * (H2 / 64);           // 256 blocks, 1 wave each
    lif_fwd_kernel<<<grid, 64, 0, stream>>>(in, v0, sp, mem, vf);
}